// Round 10
// baseline (38.470 us; speedup 1.0000x reference)
//
#include <hip/hip_runtime.h>
#include <hip/hip_bf16.h>

typedef __attribute__((ext_vector_type(8))) short short8;
typedef __attribute__((ext_vector_type(4))) float f32x4;

#define NQ 32      // queries
#define NM 32      // query tokens
#define NH 128     // head dim
#define ND 512     // docs
#define NN 180     // doc tokens
#define NT 12      // n-tiles of 16
#define TSTR 136   // LDS tile row stride in shorts (272 B)

static __device__ __forceinline__ unsigned short f2bf(float x) {
  __hip_bfloat16 h = __float2bfloat16(x);
  return __builtin_bit_cast(unsigned short, h);
}

static __device__ __forceinline__ uint4 pack8(const float* v, float m) {
  unsigned int a = (unsigned)f2bf(v[0] * m) | ((unsigned)f2bf(v[1] * m) << 16);
  unsigned int b = (unsigned)f2bf(v[2] * m) | ((unsigned)f2bf(v[3] * m) << 16);
  unsigned int c = (unsigned)f2bf(v[4] * m) | ((unsigned)f2bf(v[5] * m) << 16);
  unsigned int e = (unsigned)f2bf(v[6] * m) | ((unsigned)f2bf(v[7] * m) << 16);
  return make_uint4(a, b, c, e);
}

// Qb_frag[q][mt][ks][lane][8]: MFMA-ready Q fragments (masked, bf16).
__global__ __launch_bounds__(256) void prep_q_frag(
    const float* __restrict__ Q, const int* __restrict__ qmask,
    unsigned short* __restrict__ Qb) {
  int idx = blockIdx.x * 256 + threadIdx.x;   // 16384 fragment-lanes
  int lane = idx & 63;
  int ks = (idx >> 6) & 3;
  int mt = (idx >> 8) & 1;
  int q  = idx >> 9;
  int row = mt * 16 + (lane & 15);
  int k0  = ks * 32 + (lane >> 4) * 8;
  const float* src = Q + (q * NM + row) * NH + k0;
  float v[8];
  *reinterpret_cast<float4*>(&v[0]) = *reinterpret_cast<const float4*>(src);
  *reinterpret_cast<float4*>(&v[4]) = *reinterpret_cast<const float4*>(src + 4);
  float m = (float)qmask[q * NM + row];
  reinterpret_cast<uint4*>(Qb)[idx] = pack8(v, m);
}

// 1024 blocks x 512 threads (8 waves); block = (doc, half), XCD-paired via
// d = ((bid>>4)<<3)|(bid&7) so a doc's two halves share one XCD's L2.
// Each wave owns ONE query pair. TILE-PIPELINED staging (T14 async split):
// per n-tile each thread stages exactly one float4; loads for tile nt+1 are
// ISSUED before the MFMAs on tile nt and CONSUMED (pack+ds_write) after them,
// so the vmcnt wait lands post-compute and HBM streams continuously instead of
// the old {92KB burst; barrier; silent compute} phase serialization.
// LDS: 2 x 16-row tile buffers (8.7 KB). ~121 VGPR <= 128 -> 4 waves/SIMD.
__global__ __launch_bounds__(512, 4) void maxsim_kernel(
    const float* __restrict__ D, const int* __restrict__ dmask,
    const unsigned short* __restrict__ Qb, float* __restrict__ out) {
  __shared__ unsigned short Dlds[2][16 * TSTR];  // 2 x 4352 B
  const int bid = blockIdx.x;
  const int d    = ((bid >> 4) << 3) | (bid & 7);
  const int half = (bid >> 3) & 1;
  const int tid = threadIdx.x;
  const int lane = tid & 63;
  const int w = tid >> 6;
  const float NEG = -__builtin_inff();

  const int bl = lane & 15;   // fragment row(n)/col(m) within tile
  const int bg = lane >> 4;   // k-group / n-quarter

  // ---- issue Q-fragment loads first (from frag-ordered Qb; waitcnt folds later) ----
  const int q0 = (half * 8 + w) * 2;
  short8 Qf[2][2][4];  // [qi][mt][ks] = 64 VGPR
  #pragma unroll
  for (int qi = 0; qi < 2; ++qi)
    #pragma unroll
    for (int mt = 0; mt < 2; ++mt)
      #pragma unroll
      for (int ks = 0; ks < 4; ++ks)
        Qf[qi][mt][ks] = *reinterpret_cast<const short8*>(
            reinterpret_cast<const char*>(Qb) +
            ((((q0 + qi) * 2 + mt) * 4 + ks) << 10) + (lane << 4));

  // ---- staging geometry: one float4 per thread per tile ----
  const int sr = tid >> 5;    // row within tile (0..15)
  const int sc = tid & 31;    // float4 column (0..31)
  const float4* Dsrc = reinterpret_cast<const float4*>(D) + d * (NN * NH / 4);
  const int* dmrow = dmask + d * NN;

  // stage tile 0
  {
    float4 v = Dsrc[sr * 32 + sc];          // rows 0..15 all valid
    float m = (float)dmrow[sr];
    uint4 pk = pack8(reinterpret_cast<const float*>(&v), m);
    *reinterpret_cast<uint2*>(&Dlds[0][sr * TSTR + sc * 4]) = make_uint2(pk.x, pk.y);
    *reinterpret_cast<uint2*>(&Dlds[0][sr * TSTR + sc * 4 + 2]) = make_uint2(pk.z, pk.w);
  }
  __syncthreads();

  float run[2][2];
  #pragma unroll
  for (int qi = 0; qi < 2; ++qi)
    #pragma unroll
    for (int mt = 0; mt < 2; ++mt) run[qi][mt] = NEG;

  #pragma unroll 2
  for (int nt = 0; nt < NT; ++nt) {
    // ---- issue prefetch loads for tile nt+1 (clamped, no divergent loads) ----
    float4 pv; float pm = 0.f;
    const bool havePre = (nt + 1 < NT);
    if (havePre) {
      int grow = (nt + 1) * 16 + sr;
      int cr = grow < NN ? grow : NN - 1;   // clamp: stay in-bounds
      pv = Dsrc[cr * 32 + sc];
      pm = (grow < NN) ? (float)dmrow[cr] : 0.f;   // mask 0 zeroes pad rows
    }

    // ---- compute on tile nt (buf nt&1) ----
    const unsigned short* buf = Dlds[nt & 1];
    short8 Da[4];
    #pragma unroll
    for (int ks = 0; ks < 4; ++ks)
      Da[ks] = *reinterpret_cast<const short8*>(&buf[bl * TSTR + ks * 32 + bg * 8]);

    f32x4 acc[2][2];
    #pragma unroll
    for (int qi = 0; qi < 2; ++qi)
      #pragma unroll
      for (int mt = 0; mt < 2; ++mt) acc[qi][mt] = (f32x4){0.f, 0.f, 0.f, 0.f};

    #pragma unroll
    for (int ks = 0; ks < 4; ++ks)
      #pragma unroll
      for (int qi = 0; qi < 2; ++qi)
        #pragma unroll
        for (int mt = 0; mt < 2; ++mt)
          acc[qi][mt] = __builtin_amdgcn_mfma_f32_16x16x32_bf16(
              Da[ks], Qf[qi][mt][ks], acc[qi][mt], 0, 0, 0);

    // j-fold into scalar run; tile 11: rows n=176+bg*4+j, only bg==0 real
    const bool isTail = (nt == NT - 1);
    #pragma unroll
    for (int qi = 0; qi < 2; ++qi)
      #pragma unroll
      for (int mt = 0; mt < 2; ++mt) {
        float v = fmaxf(fmaxf(acc[qi][mt][0], acc[qi][mt][1]),
                        fmaxf(acc[qi][mt][2], acc[qi][mt][3]));
        if (isTail && bg != 0) v = NEG;
        run[qi][mt] = fmaxf(run[qi][mt], v);
      }

    // ---- consume prefetch: pack + ds_write to the other buffer ----
    if (havePre) {
      uint4 pk = pack8(reinterpret_cast<const float*>(&pv), pm);
      unsigned short* nbuf = Dlds[(nt + 1) & 1];
      *reinterpret_cast<uint2*>(&nbuf[sr * TSTR + sc * 4]) = make_uint2(pk.x, pk.y);
      *reinterpret_cast<uint2*>(&nbuf[sr * TSTR + sc * 4 + 2]) = make_uint2(pk.z, pk.w);
    }
    __syncthreads();
  }

  // ---- reduction: xor16/32 max over n-quarters, xor1..8 sum over m ----
  #pragma unroll
  for (int qi = 0; qi < 2; ++qi) {
    float a = run[qi][0];   // m = lane&15
    float b = run[qi][1];   // m = (lane&15)+16
    a = fmaxf(a, __shfl_xor(a, 16));
    a = fmaxf(a, __shfl_xor(a, 32));
    b = fmaxf(b, __shfl_xor(b, 16));
    b = fmaxf(b, __shfl_xor(b, 32));
    float s = a + b;
    s += __shfl_xor(s, 1);
    s += __shfl_xor(s, 2);
    s += __shfl_xor(s, 4);
    s += __shfl_xor(s, 8);
    if (lane == 0) out[(q0 + qi) * ND + d] = s;
  }
}

extern "C" void kernel_launch(void* const* d_in, const int* in_sizes, int n_in,
                              void* d_out, int out_size, void* d_ws, size_t ws_size,
                              hipStream_t stream) {
  const float* Q = (const float*)d_in[0];
  const float* D = (const float*)d_in[1];
  const int* qmask = (const int*)d_in[2];
  const int* dmask = (const int*)d_in[3];
  float* out = (float*)d_out;
  unsigned short* Qb = (unsigned short*)d_ws;  // 256 KB frag-ordered Q

  prep_q_frag<<<16384 / 256, 256, 0, stream>>>(Q, qmask, Qb);
  maxsim_kernel<<<ND * 2, 512, 0, stream>>>(D, dmask, Qb, out);
}

// Round 11
// 29.203 us; speedup vs baseline: 1.3173x; 1.3173x over previous
//
#include <hip/hip_runtime.h>
#include <hip/hip_bf16.h>

typedef __attribute__((ext_vector_type(8))) short short8;
typedef __attribute__((ext_vector_type(4))) float f32x4;

#define NQ 32      // queries
#define NM 32      // query tokens
#define NH 128     // head dim
#define ND 512     // docs
#define NN 180     // doc tokens
#define LSTR 136   // LDS row stride in shorts (272 B)

static __device__ __forceinline__ unsigned short f2bf(float x) {
  __hip_bfloat16 h = __float2bfloat16(x);
  return __builtin_bit_cast(unsigned short, h);
}

static __device__ __forceinline__ uint4 pack8(const float* v, float m) {
  unsigned int a = (unsigned)f2bf(v[0] * m) | ((unsigned)f2bf(v[1] * m) << 16);
  unsigned int b = (unsigned)f2bf(v[2] * m) | ((unsigned)f2bf(v[3] * m) << 16);
  unsigned int c = (unsigned)f2bf(v[4] * m) | ((unsigned)f2bf(v[5] * m) << 16);
  unsigned int e = (unsigned)f2bf(v[6] * m) | ((unsigned)f2bf(v[7] * m) << 16);
  return make_uint4(a, b, c, e);
}

// Qb_frag[q][mt][ks][lane][8]: MFMA-ready masked bf16 Q fragments.
__global__ __launch_bounds__(256) void prep_q_frag(
    const float* __restrict__ Q, const int* __restrict__ qmask,
    unsigned short* __restrict__ Qb) {
  int idx = blockIdx.x * 256 + threadIdx.x;   // 16384 fragment-lanes
  int lane = idx & 63;
  int ks = (idx >> 6) & 3;
  int mt = (idx >> 8) & 1;
  int q  = idx >> 9;
  int row = mt * 16 + (lane & 15);
  int k0  = ks * 32 + (lane >> 4) * 8;
  const float* src = Q + (q * NM + row) * NH + k0;
  float v[8];
  *reinterpret_cast<float4*>(&v[0]) = *reinterpret_cast<const float4*>(src);
  *reinterpret_cast<float4*>(&v[4]) = *reinterpret_cast<const float4*>(src + 4);
  float m = (float)qmask[q * NM + row];
  reinterpret_cast<uint4*>(Qb)[idx] = pack8(v, m);
}

// 1024 blocks x 512 threads (8 waves); block = (doc, half), XCD-paired via
// d = ((bid>>4)<<3)|(bid&7). Wave owns ONE query pair. ALGORITHMIC lever:
// doc tokens with mask==0 contribute exactly a 0 to max_n, so we COMPACT valid
// rows (ballot prefix-scan over the 180 flags), run ceil(cnt/16) tiles (~6 avg
// instead of 12 -> ~half the MFMA/LDS/HBM work), and clamp the running max
// with 0 iff cnt<180 (exact reference semantics). Tail tile masked by row<cnt.
__global__ __launch_bounds__(512, 4) void maxsim_kernel(
    const float* __restrict__ D, const int* __restrict__ dmask,
    const unsigned short* __restrict__ Qb, float* __restrict__ out) {
  __shared__ unsigned short Dlds[192 * LSTR];  // 52224 B
  __shared__ int dstrow_s[192];
  __shared__ int wtot[3];
  __shared__ int cnt_s;
  const int bid = blockIdx.x;
  const int d    = ((bid >> 4) << 3) | (bid & 7);
  const int half = (bid >> 3) & 1;
  const int tid = threadIdx.x;
  const int lane = tid & 63;
  const int w = tid >> 6;
  const float NEG = -__builtin_inff();

  const int* dmrow = dmask + d * NN;

  // ---- compaction map: dstrow[r] = prefix-count of valid rows (-1 if masked) ----
  int flag = 0;
  if (tid < NN) flag = dmrow[tid];
  if (tid < 192) {
    unsigned long long b = __ballot(flag != 0);
    int pre = __popcll(b & ((1ull << lane) - 1ull));
    if (lane == 63) wtot[w] = pre + (flag ? 1 : 0);
    dstrow_s[tid] = pre;
  }
  __syncthreads();
  if (tid == 0) cnt_s = wtot[0] + wtot[1] + wtot[2];
  if (tid < 192) {
    int base = (w >= 1 ? wtot[0] : 0) + (w >= 2 ? wtot[1] : 0);
    dstrow_s[tid] = flag ? (dstrow_s[tid] + base) : -1;
  }
  __syncthreads();
  const int cnt = cnt_s;

  // ---- stage VALID masked-doc rows -> LDS bf16, compacted (skip masked loads) ----
  const float4* Dsrc = reinterpret_cast<const float4*>(D) + d * (NN * 32);
  for (int i = tid; i < NN * 32; i += 512) {
    int row = i >> 5, c4 = i & 31;
    int dr = dstrow_s[row];
    if (dr >= 0) {
      float4 v = Dsrc[i];
      unsigned int x = (unsigned)f2bf(v.x) | ((unsigned)f2bf(v.y) << 16);
      unsigned int y = (unsigned)f2bf(v.z) | ((unsigned)f2bf(v.w) << 16);
      *reinterpret_cast<uint2*>(&Dlds[dr * LSTR + c4 * 4]) = make_uint2(x, y);
    }
  }
  __syncthreads();

  const int bl = lane & 15;   // fragment row(n)/col(m) within tile
  const int bg = lane >> 4;   // k-group / n-quarter

  // ---- this wave's query pair (frag-ordered Qb: 16B/lane coalesced) ----
  const int q0 = (half * 8 + w) * 2;
  short8 Qf[2][2][4];  // [qi][mt][ks] = 64 VGPR
  #pragma unroll
  for (int qi = 0; qi < 2; ++qi)
    #pragma unroll
    for (int mt = 0; mt < 2; ++mt)
      #pragma unroll
      for (int ks = 0; ks < 4; ++ks)
        Qf[qi][mt][ks] = *reinterpret_cast<const short8*>(
            reinterpret_cast<const char*>(Qb) +
            ((((q0 + qi) * 2 + mt) * 4 + ks) << 10) + (lane << 4));

  float run[2][2];
  #pragma unroll
  for (int qi = 0; qi < 2; ++qi)
    #pragma unroll
    for (int mt = 0; mt < 2; ++mt) run[qi][mt] = NEG;

  const int ntc = (cnt + 15) >> 4;   // compacted tile count (~6 avg)
  #pragma unroll 1
  for (int nt = 0; nt < ntc; ++nt) {
    short8 Da[4];
    #pragma unroll
    for (int ks = 0; ks < 4; ++ks)
      Da[ks] = *reinterpret_cast<const short8*>(
          &Dlds[(nt * 16 + bl) * LSTR + ks * 32 + bg * 8]);

    f32x4 acc[2][2];
    #pragma unroll
    for (int qi = 0; qi < 2; ++qi)
      #pragma unroll
      for (int mt = 0; mt < 2; ++mt) acc[qi][mt] = (f32x4){0.f, 0.f, 0.f, 0.f};

    #pragma unroll
    for (int ks = 0; ks < 4; ++ks)
      #pragma unroll
      for (int qi = 0; qi < 2; ++qi)
        #pragma unroll
        for (int mt = 0; mt < 2; ++mt)
          acc[qi][mt] = __builtin_amdgcn_mfma_f32_16x16x32_bf16(
              Da[ks], Qf[qi][mt][ks], acc[qi][mt], 0, 0, 0);

    if (nt * 16 + 16 > cnt) {
      // tail tile: lane holds rows nt*16 + bg*4 + j; valid iff j < rlim
      const int rlim = cnt - nt * 16 - bg * 4;
      #pragma unroll
      for (int qi = 0; qi < 2; ++qi)
        #pragma unroll
        for (int mt = 0; mt < 2; ++mt) {
          float vmax = NEG;
          #pragma unroll
          for (int j = 0; j < 4; ++j) {
            float v = (j < rlim) ? acc[qi][mt][j] : NEG;
            vmax = fmaxf(vmax, v);
          }
          run[qi][mt] = fmaxf(run[qi][mt], vmax);
        }
    } else {
      #pragma unroll
      for (int qi = 0; qi < 2; ++qi)
        #pragma unroll
        for (int mt = 0; mt < 2; ++mt) {
          float vmax = fmaxf(fmaxf(acc[qi][mt][0], acc[qi][mt][1]),
                             fmaxf(acc[qi][mt][2], acc[qi][mt][3]));
          run[qi][mt] = fmaxf(run[qi][mt], vmax);
        }
    }
  }

  // masked doc tokens inject an exact 0 into max_n
  if (cnt < NN) {
    #pragma unroll
    for (int qi = 0; qi < 2; ++qi)
      #pragma unroll
      for (int mt = 0; mt < 2; ++mt) run[qi][mt] = fmaxf(run[qi][mt], 0.f);
  }

  // ---- reduction: xor16/32 max over n-quarters, xor1..8 sum over m ----
  #pragma unroll
  for (int qi = 0; qi < 2; ++qi) {
    float a = run[qi][0];   // m = lane&15
    float b = run[qi][1];   // m = (lane&15)+16
    a = fmaxf(a, __shfl_xor(a, 16));
    a = fmaxf(a, __shfl_xor(a, 32));
    b = fmaxf(b, __shfl_xor(b, 16));
    b = fmaxf(b, __shfl_xor(b, 32));
    float s = a + b;
    s += __shfl_xor(s, 1);
    s += __shfl_xor(s, 2);
    s += __shfl_xor(s, 4);
    s += __shfl_xor(s, 8);
    if (lane == 0) out[(q0 + qi) * ND + d] = s;
  }
}

extern "C" void kernel_launch(void* const* d_in, const int* in_sizes, int n_in,
                              void* d_out, int out_size, void* d_ws, size_t ws_size,
                              hipStream_t stream) {
  const float* Q = (const float*)d_in[0];
  const float* D = (const float*)d_in[1];
  const int* qmask = (const int*)d_in[2];
  const int* dmask = (const int*)d_in[3];
  float* out = (float*)d_out;
  unsigned short* Qb = (unsigned short*)d_ws;  // 256 KB frag-ordered Q

  prep_q_frag<<<16384 / 256, 256, 0, stream>>>(Q, qmask, Qb);
  maxsim_kernel<<<ND * 2, 512, 0, stream>>>(D, dmask, Qb, out);
}

// Round 12
// 27.502 us; speedup vs baseline: 1.3988x; 1.0619x over previous
//
#include <hip/hip_runtime.h>
#include <hip/hip_bf16.h>

typedef __attribute__((ext_vector_type(8))) short short8;
typedef __attribute__((ext_vector_type(4))) float f32x4;

#define NQ 32      // queries
#define NM 32      // query tokens
#define NH 128     // head dim
#define ND 512     // docs
#define NN 180     // doc tokens
#define NTMAX 12   // max compacted n-tiles (192 rows)

#define QFRAG_BYTES (NQ * 2 * 4 * 64 * 16)              // 256 KB
#define DCBLK_BYTES (NTMAX * 4 * 64 * 16)               // 49152 B per doc
#define DC_OFF      QFRAG_BYTES
#define CNT_OFF     (DC_OFF + ND * DCBLK_BYTES)         // ~25.4 MB total (ws >= 268 MB)

static __device__ __forceinline__ unsigned short f2bf(float x) {
  __hip_bfloat16 h = __float2bfloat16(x);
  return __builtin_bit_cast(unsigned short, h);
}

static __device__ __forceinline__ uint4 pack8m(const float* v, float m) {
  unsigned int a = (unsigned)f2bf(v[0] * m) | ((unsigned)f2bf(v[1] * m) << 16);
  unsigned int b = (unsigned)f2bf(v[2] * m) | ((unsigned)f2bf(v[3] * m) << 16);
  unsigned int c = (unsigned)f2bf(v[4] * m) | ((unsigned)f2bf(v[5] * m) << 16);
  unsigned int e = (unsigned)f2bf(v[6] * m) | ((unsigned)f2bf(v[7] * m) << 16);
  return make_uint4(a, b, c, e);
}

static __device__ __forceinline__ uint4 pack8(float4 a, float4 b) {
  unsigned int x = (unsigned)f2bf(a.x) | ((unsigned)f2bf(a.y) << 16);
  unsigned int y = (unsigned)f2bf(a.z) | ((unsigned)f2bf(a.w) << 16);
  unsigned int z = (unsigned)f2bf(b.x) | ((unsigned)f2bf(b.y) << 16);
  unsigned int u = (unsigned)f2bf(b.z) | ((unsigned)f2bf(b.w) << 16);
  return make_uint4(x, y, z, u);
}

// Fragment layout (16x16x32 bf16, swapped operands): element (lane,j) of tile
// (t, ks) = M[t*16 + (lane&15)][ks*32 + (lane>>4)*8 + j], stored 16B/lane.
//
// prep: blocks 0..511  = doc d -> compaction map (ballot prefix-scan), then
//                        compacted bf16 frag tiles Dc[d] + cnt[d]. Valid rows
//                        only (mask==1 -> no mask multiply needed); last-tile
//                        pad rows written as zeros; pad tiles never touched.
//       blocks 512..575 = Q fragments (masked bf16), as R11.
__global__ __launch_bounds__(256) void prep_kernel(
    const float* __restrict__ Q, const float* __restrict__ D,
    const int* __restrict__ qmask, const int* __restrict__ dmask,
    unsigned short* __restrict__ Qb, char* __restrict__ Dc,
    int* __restrict__ cnt_arr) {
  const int tid = threadIdx.x;

  if (blockIdx.x < ND) {
    // ---------------- per-doc compaction + frag write ----------------
    __shared__ unsigned short mapinv[192];
    __shared__ int wtot[3];
    const int d = blockIdx.x;
    const int lane = tid & 63;
    const int w = tid >> 6;

    int flag = 0, pre = 0;
    if (tid < NN) flag = dmask[d * NN + tid];
    if (tid < 192) {
      unsigned long long b = __ballot(flag != 0);
      pre = __popcll(b & ((1ull << lane) - 1ull));
      if (lane == 63) wtot[w] = pre + (flag ? 1 : 0);
    }
    __syncthreads();
    const int cnt = wtot[0] + wtot[1] + wtot[2];
    if (tid < 192 && flag) {
      int base = (w >= 1 ? wtot[0] : 0) + (w >= 2 ? wtot[1] : 0);
      mapinv[pre + base] = (unsigned short)tid;
    }
    __syncthreads();

    const int ntc = (cnt + 15) >> 4;
    uint4* dcout = reinterpret_cast<uint4*>(Dc + (size_t)d * DCBLK_BYTES);
    // slots: [nt][ks][lane] ; one 16B frag-lane per slot, coalesced stores
    for (int s = tid; s < ntc * 256; s += 256) {
      int nt = s >> 8, ks = (s >> 6) & 3, ln = s & 63;
      int bl = ln & 15, bg = ln >> 4;
      int dr = nt * 16 + bl;
      uint4 o = make_uint4(0u, 0u, 0u, 0u);
      if (dr < cnt) {
        int sr = mapinv[dr];
        const float4* p = reinterpret_cast<const float4*>(D) +
                          (size_t)(d * NN + sr) * 32 + ks * 8 + bg * 2;
        o = pack8(p[0], p[1]);
      }
      dcout[(size_t)nt * 256 + ks * 64 + ln] = o;
    }
    if (tid == 0) cnt_arr[d] = cnt;
  } else {
    // ---------------- Q fragments ----------------
    int idx = (blockIdx.x - ND) * 256 + tid;   // 16384 fragment-lanes
    int lane = idx & 63;
    int ks = (idx >> 6) & 3;
    int mt = (idx >> 8) & 1;
    int q  = idx >> 9;
    int row = mt * 16 + (lane & 15);
    int k0  = ks * 32 + (lane >> 4) * 8;
    const float* src = Q + (q * NM + row) * NH + k0;
    float v[8];
    *reinterpret_cast<float4*>(&v[0]) = *reinterpret_cast<const float4*>(src);
    *reinterpret_cast<float4*>(&v[4]) = *reinterpret_cast<const float4*>(src + 4);
    float m = (float)qmask[q * NM + row];
    reinterpret_cast<uint4*>(Qb)[idx] = pack8m(v, m);
  }
}

// maxsim: 2048 blocks x 256 thr (4 waves), BARRIER-FREE and LDS-FREE.
// block b -> doc d = ((b>>5)<<3)|(b&7) (same XCD as prep block d: Dc L2-hot),
// pairset = (b>>3)&3; wave w owns query pair q0 = (pairset*4+w)*2.
// Per tile: 4 coalesced 1KB global loads of MFMA-ready Da + 16 MFMA + fold.
// ~115 VGPR, capped 128 by __launch_bounds__(256,4) -> 4 waves/SIMD.
__global__ __launch_bounds__(256, 4) void maxsim_kernel(
    const char* __restrict__ Dc, const int* __restrict__ cnt_arr,
    const unsigned short* __restrict__ Qb, float* __restrict__ out) {
  const int b = blockIdx.x;
  const int d = ((b >> 5) << 3) | (b & 7);
  const int ps = (b >> 3) & 3;
  const int tid = threadIdx.x;
  const int lane = tid & 63;
  const int w = tid >> 6;
  const int bg = lane >> 4;
  const float NEG = -__builtin_inff();

  const int cnt = cnt_arr[d];
  const int q0 = (ps * 4 + w) * 2;

  // Q fragments for this wave's pair (64 VGPR), coalesced 16B/lane
  short8 Qf[2][2][4];  // [qi][mt][ks]
  #pragma unroll
  for (int qi = 0; qi < 2; ++qi)
    #pragma unroll
    for (int mt = 0; mt < 2; ++mt)
      #pragma unroll
      for (int ks = 0; ks < 4; ++ks)
        Qf[qi][mt][ks] = *reinterpret_cast<const short8*>(
            reinterpret_cast<const char*>(Qb) +
            ((((q0 + qi) * 2 + mt) * 4 + ks) << 10) + (lane << 4));

  float run[2][2];
  #pragma unroll
  for (int qi = 0; qi < 2; ++qi)
    #pragma unroll
    for (int mt = 0; mt < 2; ++mt) run[qi][mt] = NEG;

  const char* Dcd = Dc + (size_t)d * DCBLK_BYTES;
  const int ntc = (cnt + 15) >> 4;

  #pragma unroll 1
  for (int nt = 0; nt < ntc; ++nt) {
    short8 Da[4];
    #pragma unroll
    for (int ks = 0; ks < 4; ++ks)
      Da[ks] = *reinterpret_cast<const short8*>(
          Dcd + (((nt * 4 + ks) << 10) + (lane << 4)));

    f32x4 acc[2][2];
    #pragma unroll
    for (int qi = 0; qi < 2; ++qi)
      #pragma unroll
      for (int mt = 0; mt < 2; ++mt) acc[qi][mt] = (f32x4){0.f, 0.f, 0.f, 0.f};

    #pragma unroll
    for (int ks = 0; ks < 4; ++ks)
      #pragma unroll
      for (int qi = 0; qi < 2; ++qi)
        #pragma unroll
        for (int mt = 0; mt < 2; ++mt)
          acc[qi][mt] = __builtin_amdgcn_mfma_f32_16x16x32_bf16(
              Da[ks], Qf[qi][mt][ks], acc[qi][mt], 0, 0, 0);

    if (nt * 16 + 16 > cnt) {
      // tail tile: lane holds rows nt*16 + bg*4 + j; valid iff j < rlim
      const int rlim = cnt - nt * 16 - bg * 4;
      #pragma unroll
      for (int qi = 0; qi < 2; ++qi)
        #pragma unroll
        for (int mt = 0; mt < 2; ++mt) {
          float vmax = NEG;
          #pragma unroll
          for (int j = 0; j < 4; ++j) {
            float v = (j < rlim) ? acc[qi][mt][j] : NEG;
            vmax = fmaxf(vmax, v);
          }
          run[qi][mt] = fmaxf(run[qi][mt], vmax);
        }
    } else {
      #pragma unroll
      for (int qi = 0; qi < 2; ++qi)
        #pragma unroll
        for (int mt = 0; mt < 2; ++mt) {
          float vmax = fmaxf(fmaxf(acc[qi][mt][0], acc[qi][mt][1]),
                             fmaxf(acc[qi][mt][2], acc[qi][mt][3]));
          run[qi][mt] = fmaxf(run[qi][mt], vmax);
        }
    }
  }

  // masked doc tokens inject an exact 0 into max_n
  if (cnt < NN) {
    #pragma unroll
    for (int qi = 0; qi < 2; ++qi)
      #pragma unroll
      for (int mt = 0; mt < 2; ++mt) run[qi][mt] = fmaxf(run[qi][mt], 0.f);
  }

  // reduction: xor16/32 max over n-quarters, xor1..8 sum over m
  #pragma unroll
  for (int qi = 0; qi < 2; ++qi) {
    float a = run[qi][0];   // m = lane&15
    float bb = run[qi][1];  // m = (lane&15)+16
    a = fmaxf(a, __shfl_xor(a, 16));
    a = fmaxf(a, __shfl_xor(a, 32));
    bb = fmaxf(bb, __shfl_xor(bb, 16));
    bb = fmaxf(bb, __shfl_xor(bb, 32));
    float s = a + bb;
    s += __shfl_xor(s, 1);
    s += __shfl_xor(s, 2);
    s += __shfl_xor(s, 4);
    s += __shfl_xor(s, 8);
    if (lane == 0) out[(q0 + qi) * ND + d] = s;
  }
}

extern "C" void kernel_launch(void* const* d_in, const int* in_sizes, int n_in,
                              void* d_out, int out_size, void* d_ws, size_t ws_size,
                              hipStream_t stream) {
  const float* Q = (const float*)d_in[0];
  const float* D = (const float*)d_in[1];
  const int* qmask = (const int*)d_in[2];
  const int* dmask = (const int*)d_in[3];
  float* out = (float*)d_out;

  unsigned short* Qb = (unsigned short*)d_ws;
  char* Dc = (char*)d_ws + DC_OFF;
  int* cnt_arr = (int*)((char*)d_ws + CNT_OFF);

  prep_kernel<<<ND + 64, 256, 0, stream>>>(Q, D, qmask, dmask, Qb, Dc, cnt_arr);
  maxsim_kernel<<<2048, 256, 0, stream>>>(Dc, cnt_arr, Qb, out);
}